// Round 2
// baseline (380.464 us; speedup 1.0000x reference)
//
#include <hip/hip_runtime.h>
#include <hip/hip_bf16.h>
#include <stdint.h>

// Problem: B=16, S=2048, H=1024, A=8 — all tensors FLOAT32 (per reference).
//   scores[b,s] = sum_n tanh( token[b,s,:]@W_top[:,n] + c[b,n] ) * v[n]
//   c[b,n] = mean_a(aspect[b,a,:]) @ W_bot[:,n] + bias[n]
//   out = token * (1 + softmax_S(scores))
// GEMM runs in bf16 MFMA (fp32 accum). A (token) is now read as f32 directly
// by the GEMM and converted to bf16 in-register before LDS write (convert_tok
// kernel eliminated, -201 MB traffic). W_top is still pre-transposed to bf16.
// No atomics, no zero-init anywhere — no dependence on memset/poison.

#define SEQ 2048
#define H 1024
#define MTOT 32768   // B*S
#define BK 32

typedef __bf16 bf16x8 __attribute__((ext_vector_type(8)));
typedef float  f32x4  __attribute__((ext_vector_type(4)));

__device__ __forceinline__ void async16(const void* g, void* l) {
  __builtin_amdgcn_global_load_lds(
      (const __attribute__((address_space(1))) unsigned*)g,
      (__attribute__((address_space(3))) unsigned*)l, 16, 0, 0);
}

__device__ __forceinline__ unsigned f2bfraw(float f) {
  unsigned x = __float_as_uint(f);
  return (x + 0x7fffu + ((x >> 16) & 1u)) >> 16;   // RN-even, finite inputs
}
__device__ __forceinline__ unsigned pk2(float x, float y) {
  return f2bfraw(x) | (f2bfraw(y) << 16);
}
__device__ __forceinline__ float fast_tanh(float x) {
  x = fminf(fmaxf(x, -40.0f), 40.0f);
  float e = __expf(2.0f * x);
  return 1.0f - 2.0f / (e + 1.0f);
}

// ---- fused prep: W_top transpose+convert  +  aspect_c partials ----------
// blocks [0,1024): WT[n][k] = bf16(W[k][n])
// blocks [1024,1280): cpart[kc][b][n] k-split partials of mean@W_bot (+bias)
__global__ __launch_bounds__(256) void prep_k(
    const float* __restrict__ W,     // [2048][1024]
    const float* __restrict__ asp,   // [16][8][1024]
    const float* __restrict__ bias,  // [1024]
    unsigned short* __restrict__ WT, // [1024 n][1024 k] bf16
    float* __restrict__ cpart) {     // [4][16][1024]
  __shared__ __align__(16) float shbuf[1312];
  const int t = threadIdx.x;
  if (blockIdx.x < 1024) {
    // ---- transpose_w ----
    float (*tile)[33] = reinterpret_cast<float(*)[33]>(shbuf);
    const int x = t & 31, y = t >> 5;          // 32 x 8
    const int n0 = (blockIdx.x & 31) * 32, k0 = (blockIdx.x >> 5) * 32;
#pragma unroll
    for (int i = 0; i < 4; ++i)
      tile[y + 8 * i][x] = W[(size_t)(k0 + y + 8 * i) * H + n0 + x];
    __syncthreads();
#pragma unroll
    for (int i = 0; i < 4; ++i)
      WT[(size_t)(n0 + y + 8 * i) * H + k0 + x] =
          (unsigned short)f2bfraw(tile[x][y + 8 * i]);
  } else {
    // ---- aspect_c ----
    const int idx = blockIdx.x - 1024;
    const int b = idx & 15, nc = (idx >> 4) & 3, kc = idx >> 6;
    const int lane = t & 63, w = t >> 6;
    float* am = shbuf;                              // [256]
    f32x4* red = reinterpret_cast<f32x4*>(shbuf + 256);  // [4][64]
    {
      const int k = kc * 256 + t;
      float s = 0.f;
#pragma unroll
      for (int a = 0; a < 8; ++a) s += asp[(size_t)(b * 8 + a) * H + k];
      am[t] = s * 0.125f;
    }
    __syncthreads();
    const int n = nc * 256 + lane * 4;
    const float* wp = W + (size_t)(H + kc * 256 + w * 64) * H + n;
    f32x4 acc = {};
#pragma unroll 8
    for (int k = 0; k < 64; ++k) {
      const f32x4 wv = *reinterpret_cast<const f32x4*>(wp + (size_t)k * H);
      const float a = am[w * 64 + k];
      acc[0] += a * wv[0]; acc[1] += a * wv[1];
      acc[2] += a * wv[2]; acc[3] += a * wv[3];
    }
    red[w * 64 + lane] = acc;
    __syncthreads();
    if (w == 0) {
      f32x4 r = red[lane];
#pragma unroll
      for (int i = 1; i < 4; ++i) {
        const f32x4 x = red[i * 64 + lane];
        r[0] += x[0]; r[1] += x[1]; r[2] += x[2]; r[3] += x[3];
      }
      if (kc == 0) {
        r[0] += bias[n];     r[1] += bias[n + 1];
        r[2] += bias[n + 2]; r[3] += bias[n + 3];
      }
      *reinterpret_cast<f32x4*>(cpart + (size_t)kc * 16 * H + b * H + n) = r;
    }
  }
}

// ---- main GEMM (bf16 MFMA, f32 A converted inline) + tanh*v reduce ------
// grid (8 n-blocks, 256 m-blocks), 256 thr (4 waves, 2x2 of 64x64 tiles).
// XCD-aware bijective swizzle: nwg=2048 = 8*256; xcd = bid%8 gets a
// contiguous m-chunk with n fastest -> A-panel reused from that XCD's L2.
// A path: global f32 -> regs (issued during prev MFMA phase, T14) ->
// bf16 pack -> ds_write_b128.  B path: global_load_lds (bf16 WT).
__global__ __launch_bounds__(256) void gemm_score(
    const float* __restrict__ tokf,           // [32768][1024] f32
    const __hip_bfloat16* __restrict__ wt,    // WT [1024 n][1024 k] bf16
    const float* __restrict__ cpart,          // [4][16][1024] (kc0 has bias)
    const float* __restrict__ v,              // [1024] f32
    float* __restrict__ part) {               // [16][32768] partial scores
  __shared__ __hip_bfloat16 As[128 * BK];     // 8 KB  [m][k]
  __shared__ __hip_bfloat16 Bs[128 * BK];     // 8 KB  [n][k]
  const int t = threadIdx.x;
  const int lane = t & 63;
  const int w = t >> 6;
  const int wm = w >> 1, wn = w & 1;
  const unsigned bidl = blockIdx.x + (blockIdx.y << 3);       // hw linear id
  const unsigned nb = ((bidl & 7u) << 8) | (bidl >> 3);       // bijective
  const int bx = nb & 7;             // n-block
  const int by = nb >> 3;            // m-block
  const int m0 = by * 128;
  const int n0 = bx * 128;
  const int bb = by >> 4;            // 16 M-blocks per batch

  f32x4 acc[4][4] = {};

  const int srow = t >> 2, scol = (t & 3) * 8;
  const float* ga = tokf + (size_t)(m0 + srow) * H + scol;
  const __hip_bfloat16* gb = wt + (size_t)(n0 + srow) * H + scol;
  __hip_bfloat16* la0 = As + t * 8;
  __hip_bfloat16* la1 = As + t * 8 + 64 * BK;
  __hip_bfloat16* lb0 = Bs + t * 8;
  __hip_bfloat16* lb1 = Bs + t * 8 + 64 * BK;

  const int quad = lane >> 4, l16 = lane & 15;

  // prologue: A(k0=0) -> regs
  f32x4 a0l = *reinterpret_cast<const f32x4*>(ga);
  f32x4 a0h = *reinterpret_cast<const f32x4*>(ga + 4);
  f32x4 a1l = *reinterpret_cast<const f32x4*>(ga + (size_t)64 * H);
  f32x4 a1h = *reinterpret_cast<const f32x4*>(ga + (size_t)64 * H + 4);

  for (int k0 = 0; k0 < H; k0 += BK) {
    __syncthreads();                           // (1) prev LDS reads done
    async16(gb + k0, lb0);
    async16(gb + k0 + (size_t)64 * H, lb1);
    uint4 r0, r1;
    r0.x = pk2(a0l[0], a0l[1]); r0.y = pk2(a0l[2], a0l[3]);
    r0.z = pk2(a0h[0], a0h[1]); r0.w = pk2(a0h[2], a0h[3]);
    r1.x = pk2(a1l[0], a1l[1]); r1.y = pk2(a1l[2], a1l[3]);
    r1.z = pk2(a1h[0], a1h[1]); r1.w = pk2(a1h[2], a1h[3]);
    *reinterpret_cast<uint4*>(la0) = r0;
    *reinterpret_cast<uint4*>(la1) = r1;
    __syncthreads();                           // (2) drains ds_write + B lds

    // T14: issue next-tile A loads now; they drain at barrier (1) next iter,
    // hidden under the MFMA phase below.
    if (k0 + BK < H) {
      a0l = *reinterpret_cast<const f32x4*>(ga + k0 + BK);
      a0h = *reinterpret_cast<const f32x4*>(ga + k0 + BK + 4);
      a1l = *reinterpret_cast<const f32x4*>(ga + k0 + BK + (size_t)64 * H);
      a1h = *reinterpret_cast<const f32x4*>(ga + k0 + BK + (size_t)64 * H + 4);
    }

    bf16x8 af[4], bf[4];
#pragma unroll
    for (int mi = 0; mi < 4; ++mi)
      af[mi] = *reinterpret_cast<const bf16x8*>(
          As + (wm * 64 + mi * 16 + l16) * BK + quad * 8);
#pragma unroll
    for (int ni = 0; ni < 4; ++ni)
      bf[ni] = *reinterpret_cast<const bf16x8*>(
          Bs + (wn * 64 + ni * 16 + l16) * BK + quad * 8);
#pragma unroll
    for (int mi = 0; mi < 4; ++mi)
#pragma unroll
      for (int ni = 0; ni < 4; ++ni)
        acc[mi][ni] = __builtin_amdgcn_mfma_f32_16x16x32_bf16(
            af[mi], bf[ni], acc[mi][ni], 0, 0, 0);
  }

  // epilogue: partial_score_row = sum_n tanh(acc + c[b][n]) * v[n]
  float vv[4], cc[4];
#pragma unroll
  for (int ni = 0; ni < 4; ++ni) {
    const int gn = n0 + wn * 64 + ni * 16 + l16;
    vv[ni] = v[gn];
    float s = cpart[(size_t)bb * H + gn];                 // kc=0 (has bias)
    s += cpart[(size_t)1 * 16 * H + bb * H + gn];
    s += cpart[(size_t)2 * 16 * H + bb * H + gn];
    s += cpart[(size_t)3 * 16 * H + bb * H + gn];
    cc[ni] = s;
  }
  const size_t pbase = ((size_t)bx * 2 + wn) * MTOT + m0;
#pragma unroll
  for (int mi = 0; mi < 4; ++mi) {
#pragma unroll
    for (int r = 0; r < 4; ++r) {
      float s = 0.f;
#pragma unroll
      for (int ni = 0; ni < 4; ++ni)
        s += fast_tanh(acc[mi][ni][r] + cc[ni]) * vv[ni];
#pragma unroll
      for (int msk = 1; msk < 16; msk <<= 1) s += __shfl_xor(s, msk, 64);
      if (l16 == 0)
        part[pbase + wm * 64 + mi * 16 + quad * 4 + r] = s;  // unique writer
    }
  }
}

// ---- softmax over S per batch (sums 16 partials), 1 block/batch ---------
// 1024 thr (16 waves), scores held in registers: one global pass, one exp.
__global__ __launch_bounds__(1024) void softmax_k(
    const float* __restrict__ part, float* __restrict__ wts) {
  const int b = blockIdx.x, t = threadIdx.x;
  const int lane = t & 63, w = t >> 6;     // 16 waves
  __shared__ float red[16];
  const int s0 = t * 2;
  float sx = 0.f, sy = 0.f;
#pragma unroll
  for (int p = 0; p < 16; ++p) {
    const float2 x = *reinterpret_cast<const float2*>(
        part + (size_t)p * MTOT + b * SEQ + s0);
    sx += x.x; sy += x.y;
  }
  float m = fmaxf(sx, sy);
#pragma unroll
  for (int o = 1; o < 64; o <<= 1) m = fmaxf(m, __shfl_xor(m, o, 64));
  if (lane == 0) red[w] = m;
  __syncthreads();
  m = red[0];
#pragma unroll
  for (int i = 1; i < 16; ++i) m = fmaxf(m, red[i]);
  __syncthreads();
  const float e0 = __expf(sx - m), e1 = __expf(sy - m);
  float sum = e0 + e1;
#pragma unroll
  for (int o = 1; o < 64; o <<= 1) sum += __shfl_xor(sum, o, 64);
  if (lane == 0) red[w] = sum;
  __syncthreads();
  sum = 0.f;
#pragma unroll
  for (int i = 0; i < 16; ++i) sum += red[i];
  const float inv = 1.0f / sum;
  float2 o2; o2.x = e0 * inv; o2.y = e1 * inv;
  *reinterpret_cast<float2*>(wts + (size_t)b * SEQ + s0) = o2;
}

// ---- out = token * (1 + weights) ----------------------------------------
__global__ __launch_bounds__(256) void scale_k(
    const float* __restrict__ tok, const float* __restrict__ wts,
    float* __restrict__ out) {
  const size_t i = ((size_t)blockIdx.x * 256 + threadIdx.x) * 4;
  const float wm = 1.0f + wts[i >> 10];          // 4 elems share a row
  const f32x4 a = *reinterpret_cast<const f32x4*>(tok + i);
  f32x4 o;
  o[0] = a[0] * wm; o[1] = a[1] * wm; o[2] = a[2] * wm; o[3] = a[3] * wm;
  *reinterpret_cast<f32x4*>(out + i) = o;
}

extern "C" void kernel_launch(void* const* d_in, const int* in_sizes, int n_in,
                              void* d_out, int out_size, void* d_ws, size_t ws_size,
                              hipStream_t stream) {
  const float* tok  = (const float*)d_in[0];
  const float* asp  = (const float*)d_in[1];
  const float* W    = (const float*)d_in[2];
  const float* bias = (const float*)d_in[3];
  const float* v    = (const float*)d_in[4];
  float* out = (float*)d_out;

  // Scratch layout inside d_out (33,554,432 f32 total), all dead by scale_k:
  //   [16,777,216 .. 16,842,752) cpart   (4 x 16 x 1024 f32)
  //   [32,505,856 .. 33,030,144) part    (16 x 32768 f32 partial scores)
  //   [33,030,144 .. 33,554,432) WT      (1M bf16)
  float*          cpart  = out + 16777216;
  float*          part   = out + 32505856;
  unsigned short* WT_u   = (unsigned short*)(out + 33030144);
  // weights must NOT alias d_out (scale_k reads it while writing out):
  // prefer d_ws; else the aspect input buffer (524KB, dead after prep_k).
  float* wts = (ws_size >= (size_t)(SEQ * 16 * 4)) ? (float*)d_ws
                                                   : (float*)d_in[1];

  prep_k<<<1280, 256, 0, stream>>>(W, asp, bias, WT_u, cpart);
  gemm_score<<<dim3(8, 256), 256, 0, stream>>>(tok, (const __hip_bfloat16*)WT_u,
                                               cpart, v, part);
  softmax_k<<<16, 1024, 0, stream>>>(part, wts);
  scale_k<<<32768, 256, 0, stream>>>(tok, wts, out);
}

// Round 4
// 363.142 us; speedup vs baseline: 1.0477x; 1.0477x over previous
//
#include <hip/hip_runtime.h>
#include <hip/hip_bf16.h>
#include <stdint.h>

// Problem: B=16, S=2048, H=1024, A=8 — all tensors FLOAT32 (per reference).
//   scores[b,s] = sum_n tanh( token[b,s,:]@W_top[:,n] + c[b,n] ) * v[n]
//   c[b,n] = mean_a(aspect[b,a,:]) @ W_bot[:,n] + bias[n]
//   out = token * (1 + softmax_S(scores))
// GEMM: bf16 MFMA (fp32 accum), both operands staged via global_load_lds.
// R3's raw-barrier/counted-vmcnt pipeline RACED -> reverted to the guide's
// verified minimum 2-phase schedule: double-buffered LDS, ONE __syncthreads
// per K-tile (its implicit vmcnt(0)+lgkmcnt(0) drain is the wait), stage of
// tile kt+1 issued BEFORE compute of tile kt so load latency hides under
// the MFMA phase. All sync is __syncthreads — no inline-asm ordering.
// No atomics, no zero-init anywhere — no dependence on memset/poison.

#define SEQ 2048
#define H 1024
#define MTOT 32768   // B*S
#define BK 32

typedef __bf16 bf16x8 __attribute__((ext_vector_type(8)));
typedef float  f32x4  __attribute__((ext_vector_type(4)));

__device__ __forceinline__ void async16(const void* g, void* l) {
  __builtin_amdgcn_global_load_lds(
      (const __attribute__((address_space(1))) unsigned*)g,
      (__attribute__((address_space(3))) unsigned*)l, 16, 0, 0);
}

__device__ __forceinline__ unsigned f2bfraw(float f) {
  unsigned x = __float_as_uint(f);
  return (x + 0x7fffu + ((x >> 16) & 1u)) >> 16;   // RN-even, finite inputs
}
__device__ __forceinline__ float fast_tanh(float x) {
  x = fminf(fmaxf(x, -40.0f), 40.0f);
  float e = __expf(2.0f * x);
  return 1.0f - 2.0f / (e + 1.0f);
}

// ---- fused prep: transpose_w + aspect_c + convert_tok -------------------
// blocks [0,1024):      WT[n][k] = bf16(W[k][n])
// blocks [1024,1280):   cpart[kc][b][n] k-split partials of mean@W_bot
// blocks [1280,17664):  token f32 -> bf16 (bulk streaming; small
//                       latency-bound blocks hide under it)
__global__ __launch_bounds__(256) void prep_all(
    const float* __restrict__ W,     // [2048][1024]
    const float* __restrict__ asp,   // [16][8][1024]
    const float* __restrict__ bias,  // [1024]
    const float* __restrict__ tok,   // [32768][1024]
    unsigned short* __restrict__ WT, // [1024 n][1024 k] bf16
    float* __restrict__ cpart,       // [4][16][1024]
    unsigned short* __restrict__ tokb) {
  __shared__ __align__(16) float shbuf[1312];
  const int t = threadIdx.x;
  if (blockIdx.x >= 1280) {
    // ---- convert_tok ----
    const size_t i = ((size_t)(blockIdx.x - 1280) * 256 + t) * 8;
    const f32x4 a = *reinterpret_cast<const f32x4*>(tok + i);
    const f32x4 b = *reinterpret_cast<const f32x4*>(tok + i + 4);
    uint4 r;
    r.x = f2bfraw(a[0]) | (f2bfraw(a[1]) << 16);
    r.y = f2bfraw(a[2]) | (f2bfraw(a[3]) << 16);
    r.z = f2bfraw(b[0]) | (f2bfraw(b[1]) << 16);
    r.w = f2bfraw(b[2]) | (f2bfraw(b[3]) << 16);
    *reinterpret_cast<uint4*>(tokb + i) = r;
  } else if (blockIdx.x < 1024) {
    // ---- transpose_w ----
    float (*tile)[33] = reinterpret_cast<float(*)[33]>(shbuf);
    const int x = t & 31, y = t >> 5;          // 32 x 8
    const int n0 = (blockIdx.x & 31) * 32, k0 = (blockIdx.x >> 5) * 32;
#pragma unroll
    for (int i = 0; i < 4; ++i)
      tile[y + 8 * i][x] = W[(size_t)(k0 + y + 8 * i) * H + n0 + x];
    __syncthreads();
#pragma unroll
    for (int i = 0; i < 4; ++i)
      WT[(size_t)(n0 + y + 8 * i) * H + k0 + x] =
          (unsigned short)f2bfraw(tile[x][y + 8 * i]);
  } else {
    // ---- aspect_c ----
    const int idx = blockIdx.x - 1024;
    const int b = idx & 15, nc = (idx >> 4) & 3, kc = idx >> 6;
    const int lane = t & 63, w = t >> 6;
    float* am = shbuf;                                   // [256]
    f32x4* red = reinterpret_cast<f32x4*>(shbuf + 256);  // [4][64]
    {
      const int k = kc * 256 + t;
      float s = 0.f;
#pragma unroll
      for (int a = 0; a < 8; ++a) s += asp[(size_t)(b * 8 + a) * H + k];
      am[t] = s * 0.125f;
    }
    __syncthreads();
    const int n = nc * 256 + lane * 4;
    const float* wp = W + (size_t)(H + kc * 256 + w * 64) * H + n;
    f32x4 acc = {};
#pragma unroll 8
    for (int k = 0; k < 64; ++k) {
      const f32x4 wv = *reinterpret_cast<const f32x4*>(wp + (size_t)k * H);
      const float a = am[w * 64 + k];
      acc[0] += a * wv[0]; acc[1] += a * wv[1];
      acc[2] += a * wv[2]; acc[3] += a * wv[3];
    }
    red[w * 64 + lane] = acc;
    __syncthreads();
    if (w == 0) {
      f32x4 r = red[lane];
#pragma unroll
      for (int i = 1; i < 4; ++i) {
        const f32x4 x = red[i * 64 + lane];
        r[0] += x[0]; r[1] += x[1]; r[2] += x[2]; r[3] += x[3];
      }
      if (kc == 0) {
        r[0] += bias[n];     r[1] += bias[n + 1];
        r[2] += bias[n + 2]; r[3] += bias[n + 3];
      }
      *reinterpret_cast<f32x4*>(cpart + (size_t)kc * 16 * H + b * H + n) = r;
    }
  }
}

// ---- main GEMM (bf16 MFMA) + tanh*v row-reduce -> partial scores --------
// grid (8 n-blocks, 256 m-blocks), 256 thr (4 waves, 2x2 of 64x64 tiles).
// XCD-aware bijective swizzle (nwg=2048=8*256) for A-panel L2 reuse.
// 2-phase schedule (guide T3 minimum recipe): per K-tile one __syncthreads
// (drains prev stage via implicit vmcnt(0)), then issue next-tile stage,
// then ds_read+MFMA current tile.
__global__ __launch_bounds__(256) void gemm_score(
    const __hip_bfloat16* __restrict__ tokb,  // [32768][1024] bf16
    const __hip_bfloat16* __restrict__ wt,    // WT [1024 n][1024 k] bf16
    const float* __restrict__ cpart,          // [4][16][1024] (kc0 has bias)
    const float* __restrict__ v,              // [1024] f32
    float* __restrict__ part) {               // [16][32768] partial scores
  __shared__ __hip_bfloat16 lds[2 * 8192];    // 32 KB: [buf][A:4096|B:4096]
  const int t = threadIdx.x;
  const int lane = t & 63;
  const int w = t >> 6;
  const int wm = w >> 1, wn = w & 1;
  const unsigned bidl = blockIdx.x + (blockIdx.y << 3);       // hw linear id
  const unsigned nb = ((bidl & 7u) << 8) | (bidl >> 3);       // bijective
  const int bx = nb & 7;             // n-block
  const int by = nb >> 3;            // m-block
  const int m0 = by * 128;
  const int n0 = bx * 128;
  const int bb = by >> 4;            // 16 M-blocks per batch

  f32x4 acc[4][4] = {};

  const int srow = t >> 2, scol = (t & 3) * 8;
  const __hip_bfloat16* ga = tokb + (size_t)(m0 + srow) * H + scol;
  const __hip_bfloat16* gb = wt + (size_t)(n0 + srow) * H + scol;
  const int quad = lane >> 4, l16 = lane & 15;

  auto stage = [&](int kt, int buf) {
    __hip_bfloat16* p = lds + buf * 8192 + t * 8;
    const int off = kt * BK;
    async16(ga + off, p);
    async16(ga + off + (size_t)64 * H, p + 2048);
    async16(gb + off, p + 4096);
    async16(gb + off + (size_t)64 * H, p + 4096 + 2048);
  };
  auto compute = [&](int buf) {
    const __hip_bfloat16* As = lds + buf * 8192;
    const __hip_bfloat16* Bs = As + 4096;
    bf16x8 af[4], bf[4];
#pragma unroll
    for (int mi = 0; mi < 4; ++mi)
      af[mi] = *reinterpret_cast<const bf16x8*>(
          As + (wm * 64 + mi * 16 + l16) * BK + quad * 8);
#pragma unroll
    for (int ni = 0; ni < 4; ++ni)
      bf[ni] = *reinterpret_cast<const bf16x8*>(
          Bs + (wn * 64 + ni * 16 + l16) * BK + quad * 8);
#pragma unroll
    for (int mi = 0; mi < 4; ++mi)
#pragma unroll
      for (int ni = 0; ni < 4; ++ni)
        acc[mi][ni] = __builtin_amdgcn_mfma_f32_16x16x32_bf16(
            af[mi], bf[ni], acc[mi][ni], 0, 0, 0);
  };

  stage(0, 0);
  int cur = 0;
  for (int kt = 0; kt < 32; ++kt) {
    // one barrier per tile; implicit vmcnt(0)+lgkmcnt(0) drains stage(kt)
    __syncthreads();
    if (kt + 1 < 32) stage(kt + 1, cur ^ 1);
    compute(cur);
    cur ^= 1;
  }

  // epilogue: partial_score_row = sum_n tanh(acc + c[b][n]) * v[n]
  float vv[4], cc[4];
#pragma unroll
  for (int ni = 0; ni < 4; ++ni) {
    const int gn = n0 + wn * 64 + ni * 16 + l16;
    vv[ni] = v[gn];
    float s = cpart[(size_t)bb * H + gn];                 // kc=0 (has bias)
    s += cpart[(size_t)1 * 16 * H + bb * H + gn];
    s += cpart[(size_t)2 * 16 * H + bb * H + gn];
    s += cpart[(size_t)3 * 16 * H + bb * H + gn];
    cc[ni] = s;
  }
  const size_t pbase = ((size_t)bx * 2 + wn) * MTOT + m0;
#pragma unroll
  for (int mi = 0; mi < 4; ++mi) {
#pragma unroll
    for (int r = 0; r < 4; ++r) {
      float s = 0.f;
#pragma unroll
      for (int ni = 0; ni < 4; ++ni)
        s += fast_tanh(acc[mi][ni][r] + cc[ni]) * vv[ni];
#pragma unroll
      for (int msk = 1; msk < 16; msk <<= 1) s += __shfl_xor(s, msk, 64);
      if (l16 == 0)
        part[pbase + wm * 64 + mi * 16 + quad * 4 + r] = s;  // unique writer
    }
  }
}

// ---- softmax over S per batch (sums 16 partials), 1 block/batch ---------
// 1024 thr (16 waves), scores held in registers: one global pass, one exp.
__global__ __launch_bounds__(1024) void softmax_k(
    const float* __restrict__ part, float* __restrict__ wts) {
  const int b = blockIdx.x, t = threadIdx.x;
  const int lane = t & 63, w = t >> 6;     // 16 waves
  __shared__ float red[16];
  const int s0 = t * 2;
  float sx = 0.f, sy = 0.f;
#pragma unroll
  for (int p = 0; p < 16; ++p) {
    const float2 x = *reinterpret_cast<const float2*>(
        part + (size_t)p * MTOT + b * SEQ + s0);
    sx += x.x; sy += x.y;
  }
  float m = fmaxf(sx, sy);
#pragma unroll
  for (int o = 1; o < 64; o <<= 1) m = fmaxf(m, __shfl_xor(m, o, 64));
  if (lane == 0) red[w] = m;
  __syncthreads();
  m = red[0];
#pragma unroll
  for (int i = 1; i < 16; ++i) m = fmaxf(m, red[i]);
  __syncthreads();
  const float e0 = __expf(sx - m), e1 = __expf(sy - m);
  float sum = e0 + e1;
#pragma unroll
  for (int o = 1; o < 64; o <<= 1) sum += __shfl_xor(sum, o, 64);
  if (lane == 0) red[w] = sum;
  __syncthreads();
  sum = 0.f;
#pragma unroll
  for (int i = 0; i < 16; ++i) sum += red[i];
  const float inv = 1.0f / sum;
  float2 o2; o2.x = e0 * inv; o2.y = e1 * inv;
  *reinterpret_cast<float2*>(wts + (size_t)b * SEQ + s0) = o2;
}

// ---- out = token * (1 + weights) ----------------------------------------
__global__ __launch_bounds__(256) void scale_k(
    const float* __restrict__ tok, const float* __restrict__ wts,
    float* __restrict__ out) {
  const size_t i = ((size_t)blockIdx.x * 256 + threadIdx.x) * 4;
  const float wm = 1.0f + wts[i >> 10];          // 4 elems share a row
  const f32x4 a = *reinterpret_cast<const f32x4*>(tok + i);
  f32x4 o;
  o[0] = a[0] * wm; o[1] = a[1] * wm; o[2] = a[2] * wm; o[3] = a[3] * wm;
  *reinterpret_cast<f32x4*>(out + i) = o;
}

extern "C" void kernel_launch(void* const* d_in, const int* in_sizes, int n_in,
                              void* d_out, int out_size, void* d_ws, size_t ws_size,
                              hipStream_t stream) {
  const float* tok  = (const float*)d_in[0];
  const float* asp  = (const float*)d_in[1];
  const float* W    = (const float*)d_in[2];
  const float* bias = (const float*)d_in[3];
  const float* v    = (const float*)d_in[4];
  float* out = (float*)d_out;

  // Scratch layout inside d_out (33,554,432 f32 total), all dead by scale_k:
  //   [0 .. 16,777,216)          tok_bf16 (33.5M bf16, read by gemm only)
  //   [16,777,216 .. 16,842,752) cpart   (4 x 16 x 1024 f32)
  //   [32,505,856 .. 33,030,144) part    (16 x 32768 f32 partial scores)
  //   [33,030,144 .. 33,554,432) WT      (1M bf16)
  unsigned short* tokb_u = (unsigned short*)out;
  float*          cpart  = out + 16777216;
  float*          part   = out + 32505856;
  unsigned short* WT_u   = (unsigned short*)(out + 33030144);
  // weights must NOT alias d_out (scale_k reads it while writing out):
  // prefer d_ws; else the aspect input buffer (524KB, dead after prep_all).
  float* wts = (ws_size >= (size_t)(SEQ * 16 * 4)) ? (float*)d_ws
                                                   : (float*)d_in[1];

  prep_all<<<17664, 256, 0, stream>>>(W, asp, bias, tok, WT_u, cpart, tokb_u);
  gemm_score<<<dim3(8, 256), 256, 0, stream>>>(
      (const __hip_bfloat16*)tokb_u, (const __hip_bfloat16*)WT_u,
      cpart, v, part);
  softmax_k<<<16, 1024, 0, stream>>>(part, wts);
  scale_k<<<32768, 256, 0, stream>>>(tok, wts, out);
}